// Round 2
// baseline (131.829 us; speedup 1.0000x reference)
//
#include <hip/hip_runtime.h>
#include <hip/hip_bf16.h>
#include <stdint.h>

// Problem constants (fixed shapes from reference: B=4096, D=256, N=2B)
#define NROWS 8192
#define DDIM  256
#define BM    256
#define BN    256
#define BK    32
#define KSTEPS (DDIM / BK)              // 8 K-tiles
#define NTILE (NROWS / BM)              // 32 tile-rows
#define NTRI  (NTILE * (NTILE + 1) / 2) // 528 upper-tri tiles
// TAU = 0.1 -> z = cos/TAU; exp(z-10) = exp2(cos*L2E/TAU - 10*L2E)
// L2E/TAU == 10*L2E == 14.4269504: e = exp2(SCEXP*(cos - 1)), one FMA + one exp.
#define SCEXP 14.4269504088896340736f

// LDS: double-buffered staging, per buffer A(16KB)+B(16KB) = 64 KB total.
// Epilogue rowAP (256 rows x 18 float2 = 36864 B) aliases dead staging.
#define SMEM_BYTES  65536
#define ROW_STRIDE2 18   // 16 partial slots + 2 pad (float2 units)

typedef __attribute__((ext_vector_type(8))) short short8;
typedef __attribute__((ext_vector_type(4))) float f32x4;

typedef const __attribute__((address_space(1))) uint32_t glb_u32;
typedef __attribute__((address_space(3))) uint32_t lds_u32;

__device__ __forceinline__ void load_lds16(const unsigned short* g, unsigned short* l) {
  // 16B per lane, LDS dest = wave-uniform base + lane*16 (HW scatter)
  __builtin_amdgcn_global_load_lds((glb_u32*)g, (lds_u32*)l, 16, 0, 0);
}

__device__ __forceinline__ unsigned short f2bf(float x) {
  __hip_bfloat16 h = __float2bfloat16(x);
  return *reinterpret_cast<unsigned short*>(&h);
}

// Kernel 1: bf16 concat(f) PRE-NORMALIZED (inv-norm folded into operands so
// the GEMM accumulator is the cosine directly), labels, zero S arrays + out.
__global__ void __launch_bounds__(256)
milnce_prep(const float* __restrict__ feat, const float* __restrict__ pos,
            const int* __restrict__ labels, unsigned short* __restrict__ fb,
            int* __restrict__ lab, float* __restrict__ S_all,
            float* __restrict__ S_pos, float* __restrict__ out) {
  const int wave = threadIdx.x >> 6;
  const int lane = threadIdx.x & 63;
  const int row  = blockIdx.x * 4 + wave;   // 2048 blocks -> 8192 rows

  const float* src = (row < 4096) ? (feat + (size_t)row * DDIM)
                                  : (pos + (size_t)(row - 4096) * DDIM);
  float4 v = ((const float4*)src)[lane];    // 4 contiguous fp32 per lane

  float ss = v.x*v.x + v.y*v.y + v.z*v.z + v.w*v.w;
  #pragma unroll
  for (int m = 1; m < 64; m <<= 1) ss += __shfl_xor(ss, m, 64);  // all lanes get sum
  const float inv = 1.0f / sqrtf(ss);

  ushort4 o;
  o.x = f2bf(v.x * inv); o.y = f2bf(v.y * inv);
  o.z = f2bf(v.z * inv); o.w = f2bf(v.w * inv);
  ((ushort4*)(fb + (size_t)row * DDIM))[lane] = o;

  const int tid = blockIdx.x * 256 + threadIdx.x;
  if (tid < NROWS) {
    lab[tid]   = labels[tid & 4095];  // concat duplicates labels
    S_all[tid] = 0.0f;
    S_pos[tid] = 0.0f;
  }
  if (tid == 0) out[0] = 0.0f;
}

// Kernel 2: fused f@f^T (bf16 MFMA) + exp2 masked sums over UPPER-TRI tiles.
// Round-6: 256x256 tile, 8 waves (2x4 grid, 128x64/wave), BK=32 dbuf (64 KB
// static LDS), phase-split K-loop (T3/T4/T5): per K-tile two phases of
// {stage-issue || ds_read -> barrier -> lgkm(0) -> setprio(1) 16xMFMA
// setprio(0) -> barrier}; tile-end vmcnt covered by ~2 phases of compute.
// 2x arithmetic intensity per staged byte vs the old 128x128 structure.
__global__ void __launch_bounds__(512, 2)
milnce_gemm(const unsigned short* __restrict__ fb, const int* __restrict__ lab,
            float* __restrict__ S_all, float* __restrict__ S_pos) {
  __shared__ __align__(16) char smem[SMEM_BYTES];
  unsigned short* lds = (unsigned short*)smem;

  // Diagonal-order tile decode: diagonal d = bj-bi, cum(d) = d*(65-d)/2.
  int t = blockIdx.x;
  int d = (int)((65.0f - sqrtf(4225.0f - 8.0f * (float)t)) * 0.5f);
  while (d * (65 - d) / 2 > t) --d;                 // fp fixups (<=1 iter)
  while ((d + 1) * (64 - d) / 2 <= t) ++d;
  const int rem = t - d * (65 - d) / 2;
  const int bi = rem, bj = rem + d;

  const int tid  = threadIdx.x;
  const int wave = tid >> 6;
  const int lane = tid & 63;
  const int quad = lane >> 4;
  const int l15  = lane & 15;
  const int wm   = wave >> 2;   // 2 row-halves of 128
  const int wn   = wave & 3;    // 4 col-quarters of 64
  const int rowBase = bi * BM;
  const int colBase = bj * BN;

  f32x4 acc[8][4];
  #pragma unroll
  for (int i = 0; i < 8; ++i)
    #pragma unroll
    for (int j = 0; j < 4; ++j) acc[i][j] = (f32x4){0.f, 0.f, 0.f, 0.f};

  // Staging (per K-tile, per matrix): 1024 slots of 16B (256 rows x 4 octets).
  // Slot s holds (r, o) with p = s>>3, j' = (s&7)^(p&7), r = 2p + (j'>>2),
  // o = j'&3  -- XOR swizzle pre-applied on the GLOBAL source address so the
  // LDS dest stays linear (global_load_lds requirement), and ds_read_b128 of
  // a 16-lane column slice hits 8 distinct bank-quads (conflict-free).
  const unsigned short *gA0, *gA1, *gB0, *gB1;
  {
    const int s0 = tid;        // rows 0..127
    const int p0 = s0 >> 3, j0 = (s0 & 7) ^ (p0 & 7);
    const int r0 = p0 * 2 + (j0 >> 2), o0 = j0 & 3;
    const int s1 = 512 + tid;  // rows 128..255
    const int p1 = s1 >> 3, j1 = (s1 & 7) ^ (p1 & 7);
    const int r1 = p1 * 2 + (j1 >> 2), o1 = j1 & 3;
    gA0 = fb + (size_t)(rowBase + r0) * DDIM + o0 * 8;
    gA1 = fb + (size_t)(rowBase + r1) * DDIM + o1 * 8;
    gB0 = fb + (size_t)(colBase + r0) * DDIM + o0 * 8;
    gB1 = fb + (size_t)(colBase + r1) * DDIM + o1 * 8;
  }
  const int dst0 = (wave * 64) * 8;         // wave-uniform dest (shorts)
  const int dst1 = (512 + wave * 64) * 8;

  auto stageA = [&](int kt1, int bufS) {
    load_lds16(gA0 + kt1 * BK, lds + bufS + dst0);
    load_lds16(gA1 + kt1 * BK, lds + bufS + dst1);
  };
  auto stageB = [&](int kt1, int bufS) {
    load_lds16(gB0 + kt1 * BK, lds + bufS + 8192 + dst0);
    load_lds16(gB1 + kt1 * BK, lds + bufS + 8192 + dst1);
  };

  // Reader offsets: row r, octet q -> slot16 = (r>>1)*8 + (((r&1)*4+q)^((r>>1)&7)).
  // (r>>1)&7 == (l15>>1)&7 since wm*64 / wn*32 are 0 mod 8.
  const int key  = ((l15 & 1) * 4 + quad) ^ ((l15 >> 1) & 7);
  const int aOff = (wm * 64 + (l15 >> 1)) * 64 + key * 8;          // shorts
  const int bOff = 8192 + (wn * 32 + (l15 >> 1)) * 64 + key * 8;   // shorts

  // Prologue: stage kt=0 into buffer 0, drain, barrier.
  stageA(0, 0); stageB(0, 0);
  asm volatile("s_waitcnt vmcnt(0)" ::: "memory");
  __builtin_amdgcn_s_barrier();

  #pragma unroll
  for (int kt = 0; kt < KSTEPS; ++kt) {
    const int bufS  = (kt & 1) * 16384;
    const int nbufS = bufS ^ 16384;
    const unsigned short* As = lds + bufS;

    short8 a[4], b[4];
    // ---- phase 0: stage A(kt+1) || read a[0..3],b[0..3]; MFMA upper half ----
    if (kt + 1 < KSTEPS) stageA(kt + 1, nbufS);
    #pragma unroll
    for (int mi = 0; mi < 4; ++mi) a[mi] = *(const short8*)&As[aOff + mi * 512];
    #pragma unroll
    for (int ni = 0; ni < 4; ++ni) b[ni] = *(const short8*)&As[bOff + ni * 512];
    __builtin_amdgcn_s_barrier();
    asm volatile("s_waitcnt lgkmcnt(0)" ::: "memory");
    __builtin_amdgcn_sched_barrier(0);
    __builtin_amdgcn_s_setprio(1);
    #pragma unroll
    for (int mi = 0; mi < 4; ++mi)
      #pragma unroll
      for (int ni = 0; ni < 4; ++ni)
        acc[mi][ni] = __builtin_amdgcn_mfma_f32_16x16x32_bf16(a[mi], b[ni], acc[mi][ni], 0, 0, 0);
    __builtin_amdgcn_s_setprio(0);
    __builtin_amdgcn_s_barrier();
    // ---- phase 1: stage B(kt+1) || read a[4..7]; MFMA lower half ----
    if (kt + 1 < KSTEPS) stageB(kt + 1, nbufS);
    #pragma unroll
    for (int mi = 0; mi < 4; ++mi) a[mi] = *(const short8*)&As[aOff + (mi + 4) * 512];
    __builtin_amdgcn_s_barrier();
    asm volatile("s_waitcnt lgkmcnt(0)" ::: "memory");
    __builtin_amdgcn_sched_barrier(0);
    __builtin_amdgcn_s_setprio(1);
    #pragma unroll
    for (int mi = 0; mi < 4; ++mi)
      #pragma unroll
      for (int ni = 0; ni < 4; ++ni)
        acc[mi + 4][ni] = __builtin_amdgcn_mfma_f32_16x16x32_bf16(a[mi], b[ni], acc[mi + 4][ni], 0, 0, 0);
    __builtin_amdgcn_s_setprio(0);
    // counted wait: kt+1's 4 staged loads were issued 1-2 phases ago (covered)
    if (kt + 1 < KSTEPS) asm volatile("s_waitcnt vmcnt(0)" ::: "memory");
    __builtin_amdgcn_s_barrier();
  }
  __syncthreads();   // staging LDS dead; safe to alias with epilogue scratch

  // Epilogue. C/D layout (16x16x32): col = lane&15, row = quad*4 + reg.
  // acc is the cosine directly: e = exp2(SCEXP*acc - SCEXP) == exp(z - 10);
  // the -10 shift cancels in log(S_all) - log(S_pos).
  float2* rowAP = (float2*)smem;   // [256 rows][18 float2]

  int cl[4], colg[4];
  #pragma unroll
  for (int ni = 0; ni < 4; ++ni) {
    colg[ni] = colBase + wn * 64 + ni * 16 + l15;
    cl[ni]   = lab[colg[ni]];
  }

  const bool offdiag = (bi != bj);
  float2 capk[4] = {{0.f,0.f},{0.f,0.f},{0.f,0.f},{0.f,0.f}};

  #pragma unroll
  for (int mi = 0; mi < 8; ++mi) {
    const int rbase = wm * 128 + mi * 16 + quad * 4;
    const int4 rl4 = *(const int4*)&lab[rowBase + rbase];
    #pragma unroll
    for (int r = 0; r < 4; ++r) {
      const int rl = (r == 0) ? rl4.x : (r == 1) ? rl4.y : (r == 2) ? rl4.z : rl4.w;
      const int rowg = rowBase + rbase + r;
      float sx = 0.f, sy = 0.f;
      #pragma unroll
      for (int ni = 0; ni < 4; ++ni) {
        float e = exp2f(__builtin_fmaf(acc[mi][ni][r], SCEXP, -SCEXP));
        if (!offdiag && rowg == colg[ni]) e = 0.f;   // mask diagonal entries
        float ep = (rl == cl[ni]) ? e : 0.f;
        capk[ni].x += e; capk[ni].y += ep;
        sx += e; sy += ep;
      }
      if (offdiag) {
        // pre-reduce across l15 (masks 4,8): lane l15<4 holds the sum over
        // its l15-mod-4 class (4 lanes x 4 ni = 16 columns of this wn).
        sx += __shfl_xor(sx, 4, 64); sx += __shfl_xor(sx, 8, 64);
        sy += __shfl_xor(sy, 4, 64); sy += __shfl_xor(sy, 8, 64);
        if (l15 < 4)
          rowAP[(rbase + r) * ROW_STRIDE2 + wn * 4 + l15] = make_float2(sx, sy);
      }
    }
  }

  // Column commit: quad-reduce (masks 16,32) -> per-wm-wave coalesced atomics.
  // Both wm waves add their 128-row halves; atomics accumulate across blocks.
  #pragma unroll
  for (int ni = 0; ni < 4; ++ni) {
    float x = capk[ni].x, y = capk[ni].y;
    x += __shfl_xor(x, 16, 64); x += __shfl_xor(x, 32, 64);
    y += __shfl_xor(y, 16, 64); y += __shfl_xor(y, 32, 64);
    if (quad == 0) {
      atomicAdd(&S_all[colg[ni]], x);
      atomicAdd(&S_pos[colg[ni]], y);
    }
  }

  __syncthreads();

  if (offdiag && tid < 256) {
    // Row commit (== skipped transposed tile's columns): sum 16 partials.
    const float2* rp = rowAP + tid * ROW_STRIDE2;
    float sx = 0.f, sy = 0.f;
    #pragma unroll
    for (int i = 0; i < 16; ++i) { sx += rp[i].x; sy += rp[i].y; }
    atomicAdd(&S_all[rowBase + tid], sx);
    atomicAdd(&S_pos[rowBase + tid], sy);
  }
}

// Kernel 3: loss = sum_i log(S_all[i]) - log(S_pos[i])  (the +10 shifts cancel).
// 32 blocks, one element per thread, one atomic per block; out zeroed by prep.
__global__ void __launch_bounds__(256)
milnce_final(const float* __restrict__ S_all, const float* __restrict__ S_pos,
             float* __restrict__ out) {
  const int i = blockIdx.x * 256 + threadIdx.x;   // 32*256 == NROWS
  float s = logf(S_all[i]) - logf(S_pos[i]);
  #pragma unroll
  for (int m = 1; m < 64; m <<= 1) s += __shfl_xor(s, m, 64);
  __shared__ float red[4];
  if ((threadIdx.x & 63) == 0) red[threadIdx.x >> 6] = s;
  __syncthreads();
  if (threadIdx.x == 0) atomicAdd(out, (red[0] + red[1]) + (red[2] + red[3]));
}

extern "C" void kernel_launch(void* const* d_in, const int* in_sizes, int n_in,
                              void* d_out, int out_size, void* d_ws, size_t ws_size,
                              hipStream_t stream) {
  const float* feat   = (const float*)d_in[0];
  const float* pos    = (const float*)d_in[1];
  const int*   labels = (const int*)d_in[2];

  char* ws = (char*)d_ws;
  unsigned short* fb    = (unsigned short*)ws;                       // 4 MB bf16 normalized concat
  int*            lab   = (int*)  (ws + 4u * 1024 * 1024);           // 32 KB
  float*          S_all = (float*)(ws + 4u * 1024 * 1024 + 32 * 1024);
  float*          S_pos = (float*)(ws + 4u * 1024 * 1024 + 64 * 1024);
  float*          out   = (float*)d_out;

  hipLaunchKernelGGL(milnce_prep, dim3(NROWS / 4), dim3(256), 0, stream,
                     feat, pos, labels, fb, lab, S_all, S_pos, out);
  hipLaunchKernelGGL(milnce_gemm, dim3(NTRI), dim3(512), 0, stream,
                     fb, lab, S_all, S_pos);
  hipLaunchKernelGGL(milnce_final, dim3(32), dim3(256), 0, stream,
                     S_all, S_pos, out);
}

// Round 3
// 130.330 us; speedup vs baseline: 1.0115x; 1.0115x over previous
//
#include <hip/hip_runtime.h>
#include <hip/hip_bf16.h>
#include <stdint.h>

// Problem constants (fixed shapes from reference: B=4096, D=256, N=2B)
#define NROWS 8192
#define DDIM  256
#define BM    256
#define BN    256
#define BK    32
#define KSTEPS (DDIM / BK)              // 8 K-tiles
#define NTILE (NROWS / BM)              // 32 tile-rows
#define NTRI  (NTILE * (NTILE + 1) / 2) // 528 upper-tri tiles
// TAU = 0.1 -> z = cos/TAU; exp(z-10) = exp2(cos*L2E/TAU - 10*L2E)
// L2E/TAU == 10*L2E == 14.4269504: e = exp2(SCEXP*(cos - 1)), one FMA + one exp.
#define SCEXP 14.4269504088896340736f

// LDS: double-buffered staging, per buffer A(16KB)+B(16KB) = 64 KB total.
// Epilogue rowAP (256 rows x 18 float2 = 36864 B) aliases dead staging.
#define SMEM_BYTES  65536
#define ROW_STRIDE2 18   // 16 partial slots + 2 pad (float2 units)

typedef __attribute__((ext_vector_type(8))) short short8;
typedef __attribute__((ext_vector_type(4))) float f32x4;

typedef const __attribute__((address_space(1))) uint32_t glb_u32;
typedef __attribute__((address_space(3))) uint32_t lds_u32;

__device__ __forceinline__ void load_lds16(const unsigned short* g, unsigned short* l) {
  // 16B per lane, LDS dest = wave-uniform base + lane*16 (HW scatter)
  __builtin_amdgcn_global_load_lds((glb_u32*)g, (lds_u32*)l, 16, 0, 0);
}

__device__ __forceinline__ unsigned short f2bf(float x) {
  __hip_bfloat16 h = __float2bfloat16(x);
  return *reinterpret_cast<unsigned short*>(&h);
}

// Kernel 1: bf16 concat(f) PRE-NORMALIZED (inv-norm folded into operands so
// the GEMM accumulator is the cosine directly), labels, zero S arrays + out.
__global__ void __launch_bounds__(256)
milnce_prep(const float* __restrict__ feat, const float* __restrict__ pos,
            const int* __restrict__ labels, unsigned short* __restrict__ fb,
            int* __restrict__ lab, float* __restrict__ S_all,
            float* __restrict__ S_pos, float* __restrict__ out) {
  const int wave = threadIdx.x >> 6;
  const int lane = threadIdx.x & 63;
  const int row  = blockIdx.x * 4 + wave;   // 2048 blocks -> 8192 rows

  const float* src = (row < 4096) ? (feat + (size_t)row * DDIM)
                                  : (pos + (size_t)(row - 4096) * DDIM);
  float4 v = ((const float4*)src)[lane];    // 4 contiguous fp32 per lane

  float ss = v.x*v.x + v.y*v.y + v.z*v.z + v.w*v.w;
  #pragma unroll
  for (int m = 1; m < 64; m <<= 1) ss += __shfl_xor(ss, m, 64);  // all lanes get sum
  const float inv = 1.0f / sqrtf(ss);

  ushort4 o;
  o.x = f2bf(v.x * inv); o.y = f2bf(v.y * inv);
  o.z = f2bf(v.z * inv); o.w = f2bf(v.w * inv);
  ((ushort4*)(fb + (size_t)row * DDIM))[lane] = o;

  const int tid = blockIdx.x * 256 + threadIdx.x;
  if (tid < NROWS) {
    lab[tid]   = labels[tid & 4095];  // concat duplicates labels
    S_all[tid] = 0.0f;
    S_pos[tid] = 0.0f;
  }
  if (tid == 0) out[0] = 0.0f;
}

// Kernel 2: fused f@f^T (bf16 MFMA) + exp2 masked sums over UPPER-TRI tiles.
// Round-7 fixes vs round-6 (which SPILLED: launch_bounds(512,2) acted as a
// 128-reg cap -> acc[8][4] went to scratch, WRITE_SIZE 36 MB, MfmaUtil 7%):
//  - __launch_bounds__(512) only: backend caps at 256 regs (8-wave
//    schedulability), acc 128 + a/b 32 + temps fit, no scratch.
//  - Counted vmcnt: stage BOTH A,B(kt+1) at phase-0 top; s_waitcnt vmcnt(4)
//    waits only kt's loads (issued a full K-tile = 2 phases earlier, latency
//    covered); kt+1's 4 stay in flight across the barrier. No vmcnt(0) in
//    the main loop.
//  - Validating barrier is asm volatile ("memory") so buffer reads can't be
//    hoisted above it; ds_reads now AFTER the barrier.
__global__ void __launch_bounds__(512)
milnce_gemm(const unsigned short* __restrict__ fb, const int* __restrict__ lab,
            float* __restrict__ S_all, float* __restrict__ S_pos) {
  __shared__ __align__(16) char smem[SMEM_BYTES];
  unsigned short* lds = (unsigned short*)smem;

  // Diagonal-order tile decode: diagonal d = bj-bi, cum(d) = d*(65-d)/2.
  int t = blockIdx.x;
  int d = (int)((65.0f - sqrtf(4225.0f - 8.0f * (float)t)) * 0.5f);
  while (d * (65 - d) / 2 > t) --d;                 // fp fixups (<=1 iter)
  while ((d + 1) * (64 - d) / 2 <= t) ++d;
  const int rem = t - d * (65 - d) / 2;
  const int bi = rem, bj = rem + d;

  const int tid  = threadIdx.x;
  const int wave = tid >> 6;
  const int lane = tid & 63;
  const int quad = lane >> 4;
  const int l15  = lane & 15;
  const int wm   = wave >> 2;   // 2 row-halves of 128
  const int wn   = wave & 3;    // 4 col-quarters of 64
  const int rowBase = bi * BM;
  const int colBase = bj * BN;

  f32x4 acc[8][4];
  #pragma unroll
  for (int i = 0; i < 8; ++i)
    #pragma unroll
    for (int j = 0; j < 4; ++j) acc[i][j] = (f32x4){0.f, 0.f, 0.f, 0.f};

  // Staging (per K-tile, per matrix): 1024 slots of 16B (256 rows x 4 octets).
  // Slot s holds (r, o) with p = s>>3, j' = (s&7)^(p&7), r = 2p + (j'>>2),
  // o = j'&3  -- XOR swizzle pre-applied on the GLOBAL source address so the
  // LDS dest stays linear (global_load_lds requirement), and ds_read_b128 of
  // a 16-lane column slice hits 8 distinct bank-quads (conflict-free).
  const unsigned short *gA0, *gA1, *gB0, *gB1;
  {
    const int s0 = tid;        // rows 0..127
    const int p0 = s0 >> 3, j0 = (s0 & 7) ^ (p0 & 7);
    const int r0 = p0 * 2 + (j0 >> 2), o0 = j0 & 3;
    const int s1 = 512 + tid;  // rows 128..255
    const int p1 = s1 >> 3, j1 = (s1 & 7) ^ (p1 & 7);
    const int r1 = p1 * 2 + (j1 >> 2), o1 = j1 & 3;
    gA0 = fb + (size_t)(rowBase + r0) * DDIM + o0 * 8;
    gA1 = fb + (size_t)(rowBase + r1) * DDIM + o1 * 8;
    gB0 = fb + (size_t)(colBase + r0) * DDIM + o0 * 8;
    gB1 = fb + (size_t)(colBase + r1) * DDIM + o1 * 8;
  }
  const int dst0 = (wave * 64) * 8;         // wave-uniform dest (shorts)
  const int dst1 = (512 + wave * 64) * 8;

  auto stageA = [&](int kt1, int bufS) {
    load_lds16(gA0 + kt1 * BK, lds + bufS + dst0);
    load_lds16(gA1 + kt1 * BK, lds + bufS + dst1);
  };
  auto stageB = [&](int kt1, int bufS) {
    load_lds16(gB0 + kt1 * BK, lds + bufS + 8192 + dst0);
    load_lds16(gB1 + kt1 * BK, lds + bufS + 8192 + dst1);
  };

  // Reader offsets: row r, octet q -> slot16 = (r>>1)*8 + (((r&1)*4+q)^((r>>1)&7)).
  // (r>>1)&7 == (l15>>1)&7 since wm*128 / wn*64 row bases are 0 mod 16.
  const int key  = ((l15 & 1) * 4 + quad) ^ ((l15 >> 1) & 7);
  const int aOff = (wm * 64 + (l15 >> 1)) * 64 + key * 8;          // shorts
  const int bOff = 8192 + (wn * 32 + (l15 >> 1)) * 64 + key * 8;   // shorts

  // Prologue: stage kt=0 into buffer 0 (waited at kt=0 phase-0, one-time stall).
  stageA(0, 0); stageB(0, 0);

  #pragma unroll
  for (int kt = 0; kt < KSTEPS; ++kt) {
    const int bufS  = (kt & 1) * 16384;
    const int nbufS = bufS ^ 16384;
    const unsigned short* As = lds + bufS;

    // ---- phase 0: stage(kt+1) -> other buffer; counted wait; MFMA upper ----
    if (kt + 1 < KSTEPS) {
      stageA(kt + 1, nbufS);
      stageB(kt + 1, nbufS);
      // kt's 4 loads (issued one full K-tile ago) landed; kt+1's stay in flight
      asm volatile("s_waitcnt vmcnt(4)" ::: "memory");
    } else {
      asm volatile("s_waitcnt vmcnt(0)" ::: "memory");
    }
    asm volatile("s_barrier" ::: "memory");    // buf[cur] now valid for all waves

    short8 a[4], b[4];
    #pragma unroll
    for (int mi = 0; mi < 4; ++mi) a[mi] = *(const short8*)&As[aOff + mi * 512];
    #pragma unroll
    for (int ni = 0; ni < 4; ++ni) b[ni] = *(const short8*)&As[bOff + ni * 512];
    asm volatile("s_waitcnt lgkmcnt(0)" ::: "memory");
    __builtin_amdgcn_sched_barrier(0);
    __builtin_amdgcn_s_setprio(1);
    #pragma unroll
    for (int mi = 0; mi < 4; ++mi)
      #pragma unroll
      for (int ni = 0; ni < 4; ++ni)
        acc[mi][ni] = __builtin_amdgcn_mfma_f32_16x16x32_bf16(a[mi], b[ni], acc[mi][ni], 0, 0, 0);
    __builtin_amdgcn_s_setprio(0);
    asm volatile("s_barrier" ::: "memory");    // convoy phase split

    // ---- phase 1: lower 128 rows, reuse b ----
    #pragma unroll
    for (int mi = 0; mi < 4; ++mi) a[mi] = *(const short8*)&As[aOff + (mi + 4) * 512];
    asm volatile("s_waitcnt lgkmcnt(0)" ::: "memory");
    __builtin_amdgcn_sched_barrier(0);
    __builtin_amdgcn_s_setprio(1);
    #pragma unroll
    for (int mi = 0; mi < 4; ++mi)
      #pragma unroll
      for (int ni = 0; ni < 4; ++ni)
        acc[mi + 4][ni] = __builtin_amdgcn_mfma_f32_16x16x32_bf16(a[mi], b[ni], acc[mi + 4][ni], 0, 0, 0);
    __builtin_amdgcn_s_setprio(0);
    // this wave's reads of buf[cur] are drained (lgkmcnt above); after the
    // barrier, next iteration may overwrite it
    asm volatile("s_barrier" ::: "memory");
  }
  __syncthreads();   // staging LDS dead; safe to alias with epilogue scratch

  // Epilogue. C/D layout (16x16x32): col = lane&15, row = quad*4 + reg.
  // acc is the cosine directly: e = exp2(SCEXP*acc - SCEXP) == exp(z - 10);
  // the -10 shift cancels in log(S_all) - log(S_pos).
  float2* rowAP = (float2*)smem;   // [256 rows][18 float2]

  int cl[4], colg[4];
  #pragma unroll
  for (int ni = 0; ni < 4; ++ni) {
    colg[ni] = colBase + wn * 64 + ni * 16 + l15;
    cl[ni]   = lab[colg[ni]];
  }

  const bool offdiag = (bi != bj);
  float2 capk[4] = {{0.f,0.f},{0.f,0.f},{0.f,0.f},{0.f,0.f}};

  #pragma unroll
  for (int mi = 0; mi < 8; ++mi) {
    const int rbase = wm * 128 + mi * 16 + quad * 4;
    const int4 rl4 = *(const int4*)&lab[rowBase + rbase];
    #pragma unroll
    for (int r = 0; r < 4; ++r) {
      const int rl = (r == 0) ? rl4.x : (r == 1) ? rl4.y : (r == 2) ? rl4.z : rl4.w;
      const int rowg = rowBase + rbase + r;
      float sx = 0.f, sy = 0.f;
      #pragma unroll
      for (int ni = 0; ni < 4; ++ni) {
        float e = exp2f(__builtin_fmaf(acc[mi][ni][r], SCEXP, -SCEXP));
        if (!offdiag && rowg == colg[ni]) e = 0.f;   // mask diagonal entries
        float ep = (rl == cl[ni]) ? e : 0.f;
        capk[ni].x += e; capk[ni].y += ep;
        sx += e; sy += ep;
      }
      if (offdiag) {
        // pre-reduce across l15 (masks 4,8): lane l15<4 holds the sum over
        // its l15-mod-4 class (4 lanes x 4 ni = 16 columns of this wn).
        sx += __shfl_xor(sx, 4, 64); sx += __shfl_xor(sx, 8, 64);
        sy += __shfl_xor(sy, 4, 64); sy += __shfl_xor(sy, 8, 64);
        if (l15 < 4)
          rowAP[(rbase + r) * ROW_STRIDE2 + wn * 4 + l15] = make_float2(sx, sy);
      }
    }
  }

  // Column commit: quad-reduce (masks 16,32) -> per-wm-wave coalesced atomics.
  // Both wm waves add their 128-row halves; atomics accumulate across blocks.
  #pragma unroll
  for (int ni = 0; ni < 4; ++ni) {
    float x = capk[ni].x, y = capk[ni].y;
    x += __shfl_xor(x, 16, 64); x += __shfl_xor(x, 32, 64);
    y += __shfl_xor(y, 16, 64); y += __shfl_xor(y, 32, 64);
    if (quad == 0) {
      atomicAdd(&S_all[colg[ni]], x);
      atomicAdd(&S_pos[colg[ni]], y);
    }
  }

  __syncthreads();

  if (offdiag && tid < 256) {
    // Row commit (== skipped transposed tile's columns): sum 16 partials.
    const float2* rp = rowAP + tid * ROW_STRIDE2;
    float sx = 0.f, sy = 0.f;
    #pragma unroll
    for (int i = 0; i < 16; ++i) { sx += rp[i].x; sy += rp[i].y; }
    atomicAdd(&S_all[rowBase + tid], sx);
    atomicAdd(&S_pos[rowBase + tid], sy);
  }
}

// Kernel 3: loss = sum_i log(S_all[i]) - log(S_pos[i])  (the +10 shifts cancel).
// 32 blocks, one element per thread, one atomic per block; out zeroed by prep.
__global__ void __launch_bounds__(256)
milnce_final(const float* __restrict__ S_all, const float* __restrict__ S_pos,
             float* __restrict__ out) {
  const int i = blockIdx.x * 256 + threadIdx.x;   // 32*256 == NROWS
  float s = logf(S_all[i]) - logf(S_pos[i]);
  #pragma unroll
  for (int m = 1; m < 64; m <<= 1) s += __shfl_xor(s, m, 64);
  __shared__ float red[4];
  if ((threadIdx.x & 63) == 0) red[threadIdx.x >> 6] = s;
  __syncthreads();
  if (threadIdx.x == 0) atomicAdd(out, (red[0] + red[1]) + (red[2] + red[3]));
}

extern "C" void kernel_launch(void* const* d_in, const int* in_sizes, int n_in,
                              void* d_out, int out_size, void* d_ws, size_t ws_size,
                              hipStream_t stream) {
  const float* feat   = (const float*)d_in[0];
  const float* pos    = (const float*)d_in[1];
  const int*   labels = (const int*)d_in[2];

  char* ws = (char*)d_ws;
  unsigned short* fb    = (unsigned short*)ws;                       // 4 MB bf16 normalized concat
  int*            lab   = (int*)  (ws + 4u * 1024 * 1024);           // 32 KB
  float*          S_all = (float*)(ws + 4u * 1024 * 1024 + 32 * 1024);
  float*          S_pos = (float*)(ws + 4u * 1024 * 1024 + 64 * 1024);
  float*          out   = (float*)d_out;

  hipLaunchKernelGGL(milnce_prep, dim3(NROWS / 4), dim3(256), 0, stream,
                     feat, pos, labels, fb, lab, S_all, S_pos, out);
  hipLaunchKernelGGL(milnce_gemm, dim3(NTRI), dim3(512), 0, stream,
                     fb, lab, S_all, S_pos);
  hipLaunchKernelGGL(milnce_final, dim3(32), dim3(256), 0, stream,
                     S_all, S_pos, out);
}